// Round 8
// baseline (2578.891 us; speedup 1.0000x reference)
//
#include <hip/hip_runtime.h>

#define T_STEPS 512
#define H_DIM   2048
#define G_DIM   8192   // 4*H
#define NGUESS  4096
#define NWG     256
#define NTHR    512    // 8 waves; wave u owns unit base+u

typedef unsigned long long u64;

// exp2-based fast activations (v_exp_f32 + v_rcp_f32), saturation-safe.
#define LOG2E 1.4426950408889634f
__device__ __forceinline__ float fast_sig(float x) {
    return __builtin_amdgcn_rcpf(1.0f + __builtin_amdgcn_exp2f(-LOG2E * x));
}
__device__ __forceinline__ float fast_tanh(float x) {
    float t = __builtin_amdgcn_exp2f(2.0f * LOG2E * x);
    return 1.0f - 2.0f * __builtin_amdgcn_rcpf(t + 1.0f);
}

#define ALOAD(p)    __hip_atomic_load((p), __ATOMIC_RELAXED, __HIP_MEMORY_SCOPE_AGENT)
#define ASTORE(p,v) __hip_atomic_store((p), (v), __ATOMIC_RELAXED, __HIP_MEMORY_SCOPE_AGENT)

// ---------------------------------------------------------------------------
// Kernel 1: gather embeddings -> xs[T][2048]
// ---------------------------------------------------------------------------
__global__ void embed_kernel(const int* __restrict__ guesses,
                             const int* __restrict__ feedbacks,
                             const float* __restrict__ gemb,
                             const float* __restrict__ femb,
                             float* __restrict__ xs) {
    int t = blockIdx.x;                      // 512 blocks
    int g = guesses[t];
    int f = feedbacks[t];
    const float4* gs = (const float4*)(gemb + (size_t)g * 1024);
    const float4* fs = (const float4*)(femb + (size_t)f * 1024);
    float4* xg = (float4*)(xs + (size_t)t * H_DIM);
    int tid = threadIdx.x;                   // 256 threads
    xg[tid]       = gs[tid];
    xg[256 + tid] = fs[tid];
}

// ---------------------------------------------------------------------------
// Kernel 2: GX[t][r] = dot(W_ih[r], xs[t]) + b_ih[r] + b_hh[r]
// ---------------------------------------------------------------------------
__global__ void gx_gemm(const float* __restrict__ xs,
                        const float* __restrict__ Wih,
                        const float* __restrict__ bih,
                        const float* __restrict__ bhh,
                        float* __restrict__ GX) {
    __shared__ float As[64][17];
    __shared__ float Bs[64][17];
    int r0 = blockIdx.x * 64;
    int t0 = blockIdx.y * 64;
    int tid = threadIdx.x;
    int tx = tid & 15;
    int ty = tid >> 4;
    int lr = tid >> 2;
    int lk = (tid & 3) * 4;
    float acc[4][4] = {};

    for (int k0 = 0; k0 < H_DIM; k0 += 16) {
        const float* xp = xs  + (size_t)(t0 + lr) * H_DIM + k0 + lk;
        const float* wp = Wih + (size_t)(r0 + lr) * H_DIM + k0 + lk;
        As[lr][lk + 0] = xp[0]; As[lr][lk + 1] = xp[1];
        As[lr][lk + 2] = xp[2]; As[lr][lk + 3] = xp[3];
        Bs[lr][lk + 0] = wp[0]; Bs[lr][lk + 1] = wp[1];
        Bs[lr][lk + 2] = wp[2]; Bs[lr][lk + 3] = wp[3];
        __syncthreads();
#pragma unroll
        for (int kk = 0; kk < 16; ++kk) {
            float a[4], b[4];
#pragma unroll
            for (int i = 0; i < 4; ++i) a[i] = As[ty * 4 + i][kk];
#pragma unroll
            for (int j = 0; j < 4; ++j) b[j] = Bs[tx * 4 + j][kk];
#pragma unroll
            for (int i = 0; i < 4; ++i)
#pragma unroll
                for (int j = 0; j < 4; ++j) acc[i][j] += a[i] * b[j];
        }
        __syncthreads();
    }
#pragma unroll
    for (int i = 0; i < 4; ++i)
#pragma unroll
        for (int j = 0; j < 4; ++j) {
            int t = t0 + ty * 4 + i;
            int r = r0 + tx * 4 + j;
            GX[(size_t)t * G_DIM + r] = acc[i][j] + bih[r] + bhh[r];
        }
}

// ---------------------------------------------------------------------------
// Kernel 3: sequential LSTM. 256 WGs x 512 threads (8 waves).
//  - Wave u owns ALL 4 gate rows of unit base+u: after the in-wave shfl
//    reduce, lane 0 computes the full cell epilogue and publishes the tagged
//    h word. No gates-LDS hop, no second barrier.
//  - Poll: R3-proven pattern — thread polls words tid+512k serially; each
//    poll instruction is a coalesced 512B wave access; sleep(1) between
//    retries (minimum spin traffic).
//  - h_lds double-buffered by parity -> ONE __syncthreads per step.
//    Race-freedom without a post-dot barrier: a wave's staging writes for
//    step t+1 are gated by its polls for tag t+1; tag-(t+1) words exist only
//    after every wave grid-wide (incl. this WG) finished its dot of step t
//    and stored. Hence no wave can overwrite h_lds[p^1]... it writes the
//    OTHER parity buffer anyway, and slot overwrite (tag t+2 over tag t)
//    requires all WGs past their step-t staging (same dataflow argument as
//    the 2-slot proof).
//  - Data word: (step<<32)|float_bits; hseq memset per call -> no ABA.
// ---------------------------------------------------------------------------
__global__ void __launch_bounds__(NTHR, 2)
lstm_loop(const float* __restrict__ Whh,
          const float* __restrict__ GX,
          const float* __restrict__ xs,
          u64* __restrict__ hseq,       // [2][H_DIM] packed (seq, value)
          float* __restrict__ hfinal) { // [H_DIM] final h
    __shared__ float h_lds[2][H_DIM];   // parity double buffer

    const int wg   = blockIdx.x;        // 256
    const int base = wg * 8;
    const int tid  = threadIdx.x;       // 0..511
    const int lane = tid & 63;
    const int wv   = tid >> 6;          // wave 0..7 == local unit
    const int unit = base + wv;

    // ---- preload the 4 gate rows of `unit` as float4 (k = j*256+4l+m) ----
    float4 wreg[4][8];
#pragma unroll
    for (int g = 0; g < 4; ++g) {
        const float4* W =
            (const float4*)(Whh + (size_t)(g * H_DIM + unit) * H_DIM) + lane;
#pragma unroll
        for (int j = 0; j < 8; ++j)
            wreg[g][j] = W[j * 64];
    }

    // ---- peeled t=0: h==0 -> gates = GX[0], c_in = 0 ----
    if (lane == 0) {
        float gi = GX[0 * H_DIM + unit];
        float gg = GX[2 * H_DIM + unit];
        float go = GX[3 * H_DIM + unit];
        float c  = fast_sig(gi) * fast_tanh(gg);
        float hn = fast_sig(go) * fast_tanh(c);
        ASTORE(hseq + H_DIM + unit, (1ull << 32) | (u64)__float_as_uint(hn));
    }

    for (int t = 1; t < T_STEPS; ++t) {
        // epilogue operands: issue early, resolve under the poll (lane 0 only)
        float gxv0 = 0.f, gxv1 = 0.f, gxv2 = 0.f, gxv3 = 0.f, c_in = 0.f;
        if (lane == 0) {
            const float* gx = GX + (size_t)t * G_DIM + unit;
            gxv0 = gx[0 * H_DIM];
            gxv1 = gx[1 * H_DIM];
            gxv2 = gx[2 * H_DIM];
            gxv3 = gx[3 * H_DIM];
            c_in = xs[(size_t)t * H_DIM + unit];
        }

        // ---- poll 4 words serially; each round coalesced (stride 512) ----
        u64* slot = hseq + (size_t)(t & 1) * H_DIM;
        const unsigned want = (unsigned)t;
        float* hl = h_lds[t & 1];
#pragma unroll
        for (int k = 0; k < 4; ++k) {
            const int idx = tid + k * 512;
            u64 w = ALOAD(slot + idx);
            while ((unsigned)(w >> 32) != want) {
                __builtin_amdgcn_s_sleep(1);
                w = ALOAD(slot + idx);
            }
            hl[idx] = __uint_as_float((unsigned)w);
        }
        __syncthreads();   // B1 — the only barrier in the step

        // ---- dot: 4 gate rows of `unit`, ds_read_b128 ----
        const float4* h4p = (const float4*)hl;
        float a0 = 0.f, a1 = 0.f, a2 = 0.f, a3 = 0.f;
#pragma unroll
        for (int j = 0; j < 8; ++j) {
            float4 h4 = h4p[j * 64 + lane];
            a0 += wreg[0][j].x * h4.x + wreg[0][j].y * h4.y +
                  wreg[0][j].z * h4.z + wreg[0][j].w * h4.w;
            a1 += wreg[1][j].x * h4.x + wreg[1][j].y * h4.y +
                  wreg[1][j].z * h4.z + wreg[1][j].w * h4.w;
            a2 += wreg[2][j].x * h4.x + wreg[2][j].y * h4.y +
                  wreg[2][j].z * h4.z + wreg[2][j].w * h4.w;
            a3 += wreg[3][j].x * h4.x + wreg[3][j].y * h4.y +
                  wreg[3][j].z * h4.z + wreg[3][j].w * h4.w;
        }
#pragma unroll
        for (int off = 32; off > 0; off >>= 1) {
            a0 += __shfl_xor(a0, off, 64);
            a1 += __shfl_xor(a1, off, 64);
            a2 += __shfl_xor(a2, off, 64);
            a3 += __shfl_xor(a3, off, 64);
        }

        // ---- fused epilogue in lane 0: full cell + publish ----
        if (lane == 0) {
            float gi = a0 + gxv0;
            float gf = a1 + gxv1;
            float gg = a2 + gxv2;
            float go = a3 + gxv3;
            float c  = fast_sig(gf) * c_in + fast_sig(gi) * fast_tanh(gg);
            float hn = fast_sig(go) * fast_tanh(c);
            u64 word = ((u64)(unsigned)(t + 1) << 32) | (u64)__float_as_uint(hn);
            ASTORE(hseq + (size_t)((t + 1) & 1) * H_DIM + unit, word);
            if (t == T_STEPS - 1)
                hfinal[unit] = hn;   // kernel-end release publishes this
        }
        // no trailing barrier: staging(t+1) targets the other parity buffer
        // and is gated by the global tag-(t+1) polls.
    }
}

// ---------------------------------------------------------------------------
// Kernel 4: logits[r] = dot(W_fc[r], h) + b_fc[r]
// ---------------------------------------------------------------------------
__global__ void fc_kernel(const float* __restrict__ Wfc,
                          const float* __restrict__ bfc,
                          const float* __restrict__ h,
                          float* __restrict__ logits) {
    int wg = blockIdx.x;           // 256
    int tid = threadIdx.x;
    int lane = tid & 63, wv = tid >> 6;
    int r0 = wg * 16;
    const float4* hv = (const float4*)h;
    for (int rr = wv; rr < 16; rr += 4) {
        int r = r0 + rr;
        const float4* wrow = (const float4*)(Wfc + (size_t)r * H_DIM);
        float acc = 0.0f;
#pragma unroll
        for (int c = 0; c < 8; ++c) {
            float4 w4 = wrow[c * 64 + lane];
            float4 h4 = hv[c * 64 + lane];
            acc += w4.x * h4.x + w4.y * h4.y + w4.z * h4.z + w4.w * h4.w;
        }
#pragma unroll
        for (int off = 32; off > 0; off >>= 1) acc += __shfl_xor(acc, off, 64);
        if (lane == 0) logits[r] = acc + bfc[r];
    }
}

// ---------------------------------------------------------------------------
// Kernel 5: softmax over 4096 logits -> out
// ---------------------------------------------------------------------------
__global__ void softmax_kernel(const float* __restrict__ logits,
                               float* __restrict__ out) {
    __shared__ float sm[8];
    int tid = threadIdx.x, lane = tid & 63, wv = tid >> 6;
    float m = -1e30f;
    for (int i = tid; i < NGUESS; i += 256) m = fmaxf(m, logits[i]);
#pragma unroll
    for (int off = 32; off > 0; off >>= 1) m = fmaxf(m, __shfl_xor(m, off, 64));
    if (lane == 0) sm[wv] = m;
    __syncthreads();
    m = fmaxf(fmaxf(sm[0], sm[1]), fmaxf(sm[2], sm[3]));
    float s = 0.0f;
    for (int i = tid; i < NGUESS; i += 256) s += expf(logits[i] - m);
#pragma unroll
    for (int off = 32; off > 0; off >>= 1) s += __shfl_xor(s, off, 64);
    if (lane == 0) sm[4 + wv] = s;
    __syncthreads();
    s = sm[4] + sm[5] + sm[6] + sm[7];
    float inv = 1.0f / s;
    for (int i = tid; i < NGUESS; i += 256) out[i] = expf(logits[i] - m) * inv;
}

// ---------------------------------------------------------------------------
extern "C" void kernel_launch(void* const* d_in, const int* in_sizes, int n_in,
                              void* d_out, int out_size, void* d_ws, size_t ws_size,
                              hipStream_t stream) {
    const int*   guesses   = (const int*)d_in[0];
    const int*   feedbacks = (const int*)d_in[1];
    const float* gemb      = (const float*)d_in[2];
    const float* femb      = (const float*)d_in[3];
    const float* Wih       = (const float*)d_in[4];
    const float* Whh       = (const float*)d_in[5];
    const float* bih       = (const float*)d_in[6];
    const float* bhh       = (const float*)d_in[7];
    const float* Wfc       = (const float*)d_in[8];
    const float* bfc       = (const float*)d_in[9];

    float* ws     = (float*)d_ws;
    float* xs     = ws;                              // 512*2048 f   (4 MB)
    float* GX     = xs + (size_t)T_STEPS * H_DIM;    // 512*8192 f   (16 MB)
    u64*   hseq   = (u64*)(GX + (size_t)T_STEPS * G_DIM);  // 2*2048 u64
    float* hfinal = (float*)(hseq + 2 * H_DIM);      // 2048 f
    float* logits = hfinal + H_DIM;                  // 4096 f
    float* out    = (float*)d_out;

    // reset seq tags every call (graph replays include this) -> no ABA
    hipMemsetAsync(hseq, 0, 2 * H_DIM * sizeof(u64), stream);

    embed_kernel<<<T_STEPS, 256, 0, stream>>>(guesses, feedbacks, gemb, femb, xs);

    dim3 g2(G_DIM / 64, T_STEPS / 64);               // 128 x 8
    gx_gemm<<<g2, 256, 0, stream>>>(xs, Wih, bih, bhh, GX);

    {
        // cooperative launch solely for the co-residency guarantee
        void* args[] = { (void*)&Whh, (void*)&GX, (void*)&xs,
                         (void*)&hseq, (void*)&hfinal };
        hipLaunchCooperativeKernel((const void*)lstm_loop, dim3(NWG), dim3(NTHR),
                                   args, 0, stream);
    }

    fc_kernel<<<NGUESS / 16, 256, 0, stream>>>(Wfc, bfc, hfinal, logits);
    softmax_kernel<<<1, 256, 0, stream>>>(logits, out);
}

// Round 9
// 1734.747 us; speedup vs baseline: 1.4866x; 1.4866x over previous
//
#include <hip/hip_runtime.h>

#define T_STEPS 512
#define H_DIM   2048
#define G_DIM   8192   // 4*H
#define NGUESS  4096
#define NWG     256

typedef unsigned long long u64;

// exp2-based fast activations (v_exp_f32 + v_rcp_f32), saturation-safe.
#define LOG2E 1.4426950408889634f
__device__ __forceinline__ float fast_sig(float x) {
    return __builtin_amdgcn_rcpf(1.0f + __builtin_amdgcn_exp2f(-LOG2E * x));
}
__device__ __forceinline__ float fast_tanh(float x) {
    float t = __builtin_amdgcn_exp2f(2.0f * LOG2E * x);
    return 1.0f - 2.0f * __builtin_amdgcn_rcpf(t + 1.0f);
}

#define ALOAD(p)    __hip_atomic_load((p), __ATOMIC_RELAXED, __HIP_MEMORY_SCOPE_AGENT)
#define ASTORE(p,v) __hip_atomic_store((p), (v), __ATOMIC_RELAXED, __HIP_MEMORY_SCOPE_AGENT)

// ---------------------------------------------------------------------------
// Kernel 1: gather embeddings -> xs[T][2048]
// ---------------------------------------------------------------------------
__global__ void embed_kernel(const int* __restrict__ guesses,
                             const int* __restrict__ feedbacks,
                             const float* __restrict__ gemb,
                             const float* __restrict__ femb,
                             float* __restrict__ xs) {
    int t = blockIdx.x;                      // 512 blocks
    int g = guesses[t];
    int f = feedbacks[t];
    const float4* gs = (const float4*)(gemb + (size_t)g * 1024);
    const float4* fs = (const float4*)(femb + (size_t)f * 1024);
    float4* xg = (float4*)(xs + (size_t)t * H_DIM);
    int tid = threadIdx.x;                   // 256 threads
    xg[tid]       = gs[tid];
    xg[256 + tid] = fs[tid];
}

// ---------------------------------------------------------------------------
// Kernel 2: GX[t][r] = dot(W_ih[r], xs[t]) + b_ih[r] + b_hh[r]
// ---------------------------------------------------------------------------
__global__ void gx_gemm(const float* __restrict__ xs,
                        const float* __restrict__ Wih,
                        const float* __restrict__ bih,
                        const float* __restrict__ bhh,
                        float* __restrict__ GX) {
    __shared__ float As[64][17];
    __shared__ float Bs[64][17];
    int r0 = blockIdx.x * 64;
    int t0 = blockIdx.y * 64;
    int tid = threadIdx.x;
    int tx = tid & 15;
    int ty = tid >> 4;
    int lr = tid >> 2;
    int lk = (tid & 3) * 4;
    float acc[4][4] = {};

    for (int k0 = 0; k0 < H_DIM; k0 += 16) {
        const float* xp = xs  + (size_t)(t0 + lr) * H_DIM + k0 + lk;
        const float* wp = Wih + (size_t)(r0 + lr) * H_DIM + k0 + lk;
        As[lr][lk + 0] = xp[0]; As[lr][lk + 1] = xp[1];
        As[lr][lk + 2] = xp[2]; As[lr][lk + 3] = xp[3];
        Bs[lr][lk + 0] = wp[0]; Bs[lr][lk + 1] = wp[1];
        Bs[lr][lk + 2] = wp[2]; Bs[lr][lk + 3] = wp[3];
        __syncthreads();
#pragma unroll
        for (int kk = 0; kk < 16; ++kk) {
            float a[4], b[4];
#pragma unroll
            for (int i = 0; i < 4; ++i) a[i] = As[ty * 4 + i][kk];
#pragma unroll
            for (int j = 0; j < 4; ++j) b[j] = Bs[tx * 4 + j][kk];
#pragma unroll
            for (int i = 0; i < 4; ++i)
#pragma unroll
                for (int j = 0; j < 4; ++j) acc[i][j] += a[i] * b[j];
        }
        __syncthreads();
    }
#pragma unroll
    for (int i = 0; i < 4; ++i)
#pragma unroll
        for (int j = 0; j < 4; ++j) {
            int t = t0 + ty * 4 + i;
            int r = r0 + tx * 4 + j;
            GX[(size_t)t * G_DIM + r] = acc[i][j] + bih[r] + bhh[r];
        }
}

// ---------------------------------------------------------------------------
// Kernel 3: sequential LSTM — R3 structure (measured best) with ONE change:
// the dot reads h via ds_read_b128 (float4) instead of 32 scalar ds_read_b32.
//   - 256 WGs x 1024 threads (16 waves, 1 WG/CU). Wave v owns gate rows
//     2v, 2v+1; lane l holds W elements k = j*256 + 4l + m as float4 w[8].
//   - Poll (R3-proven): each thread serially polls tagged words tid and
//     tid+1024 (each poll instruction = coalesced 8 KB wave access),
//     sleep(1) between retries.
//   - B1 -> b128 dot -> shfl reduce -> gates LDS -> B2 -> single-wave
//     epilogue (tid<8) -> ONE coalesced 64 B tagged publish per WG.
// Data word: (step<<32)|float_bits, double-buffered by parity; memset per
// call -> no ABA across graph replays. 2-slot overwrite safety: a WG
// publishes step t+1 only after consuming all of step t.
// ---------------------------------------------------------------------------
__global__ void __launch_bounds__(1024, 4)
lstm_loop(const float* __restrict__ Whh,
          const float* __restrict__ GX,
          const float* __restrict__ xs,
          u64* __restrict__ hseq,       // [2][H_DIM] packed (seq, value)
          float* __restrict__ hfinal) { // [H_DIM] final h
    __shared__ float4 h_lds4[H_DIM / 4];   // h as float4 (8 KB)
    __shared__ float gates[32];

    const int wg   = blockIdx.x;        // 256
    const int base = wg * 8;            // unit base
    const int tid  = threadIdx.x;       // 0..1023
    const int lane = tid & 63;
    const int wv   = tid >> 6;          // wave 0..15

    const int r0 = 2 * wv;              // gate rows (gate = r>>3, unit = r&7)
    const int r1 = 2 * wv + 1;
    const int grow0 = (r0 >> 3) * H_DIM + base + (r0 & 7);
    const int grow1 = (r1 >> 3) * H_DIM + base + (r1 & 7);

    // ---- preload W_hh rows as float4 (lane l: k = j*256 + 4l + m) ----
    float4 w0[8], w1[8];
    {
        const float4* W0 = (const float4*)(Whh + (size_t)grow0 * H_DIM) + lane;
        const float4* W1 = (const float4*)(Whh + (size_t)grow1 * H_DIM) + lane;
#pragma unroll
        for (int j = 0; j < 8; ++j) {
            w0[j] = W0[j * 64];
            w1[j] = W1[j * 64];
        }
    }

    // ---- peeled step t=0: h==0, gates = GX[0] ----
    if (tid < 32)
        gates[tid] = GX[(tid >> 3) * H_DIM + base + (tid & 7)];
    __syncthreads();
    if (tid < 8) {
        int u = tid;
        float gi = gates[0 * 8 + u];
        float gg = gates[2 * 8 + u];
        float go = gates[3 * 8 + u];
        float c  = fast_sig(gi) * fast_tanh(gg);       // c_in = 0 at t=0
        float hn = fast_sig(go) * fast_tanh(c);
        u64 word = (1ull << 32) | (u64)__float_as_uint(hn);
        ASTORE(hseq + H_DIM + base + u, word);
    }

    for (int t = 1; t < T_STEPS; ++t) {
        const float* gx = GX + (size_t)t * G_DIM;
        // independent loads issued early (hide under the poll)
        float gxv0 = gx[grow0];
        float gxv1 = gx[grow1];
        float c_in = 0.0f;
        if (tid < 8) c_in = xs[(size_t)t * H_DIM + base + tid];

        // ---- serial 2-word poll (R3 pattern; each round coalesced) ----
        u64* slot = hseq + (size_t)(t & 1) * H_DIM;
        const unsigned want = (unsigned)t;
        u64 wa = ALOAD(slot + tid);
        while ((unsigned)(wa >> 32) != want) {
            __builtin_amdgcn_s_sleep(1);
            wa = ALOAD(slot + tid);
        }
        u64 wb = ALOAD(slot + tid + 1024);
        while ((unsigned)(wb >> 32) != want) {
            __builtin_amdgcn_s_sleep(1);
            wb = ALOAD(slot + tid + 1024);
        }
        {
            float* hl = (float*)h_lds4;
            hl[tid]        = __uint_as_float((unsigned)wa);
            hl[tid + 1024] = __uint_as_float((unsigned)wb);
        }
        __syncthreads();   // B1

        // ---- dot: 2 rows per wave, 8 x ds_read_b128 ----
        float acc0 = 0.0f, acc1 = 0.0f;
#pragma unroll
        for (int j = 0; j < 8; ++j) {
            float4 h4 = h_lds4[j * 64 + lane];
            acc0 += w0[j].x * h4.x + w0[j].y * h4.y +
                    w0[j].z * h4.z + w0[j].w * h4.w;
            acc1 += w1[j].x * h4.x + w1[j].y * h4.y +
                    w1[j].z * h4.z + w1[j].w * h4.w;
        }
#pragma unroll
        for (int off = 32; off > 0; off >>= 1) {
            acc0 += __shfl_xor(acc0, off, 64);
            acc1 += __shfl_xor(acc1, off, 64);
        }
        if (lane == 0) {
            gates[r0] = acc0 + gxv0;
            gates[r1] = acc1 + gxv1;
        }
        __syncthreads();   // B2

        if (tid < 8) {
            int u = tid;
            float gi = gates[0 * 8 + u];
            float gf = gates[1 * 8 + u];
            float gg = gates[2 * 8 + u];
            float go = gates[3 * 8 + u];
            float c  = fast_sig(gf) * c_in + fast_sig(gi) * fast_tanh(gg);
            float hn = fast_sig(go) * fast_tanh(c);
            u64 word = ((u64)(unsigned)(t + 1) << 32) | (u64)__float_as_uint(hn);
            ASTORE(hseq + (size_t)((t + 1) & 1) * H_DIM + base + u, word);
            if (t == T_STEPS - 1)
                hfinal[base + u] = hn;   // kernel-end release publishes this
        }
        // no trailing barrier: t+1 polls self-synchronize; h_lds/gates writes
        // at t+1 are ordered by B1(t+1)/B2(t+1) against this step's readers.
    }
}

// ---------------------------------------------------------------------------
// Kernel 4: logits[r] = dot(W_fc[r], h) + b_fc[r]
// ---------------------------------------------------------------------------
__global__ void fc_kernel(const float* __restrict__ Wfc,
                          const float* __restrict__ bfc,
                          const float* __restrict__ h,
                          float* __restrict__ logits) {
    int wg = blockIdx.x;           // 256
    int tid = threadIdx.x;
    int lane = tid & 63, wv = tid >> 6;
    int r0 = wg * 16;
    const float4* hv = (const float4*)h;
    for (int rr = wv; rr < 16; rr += 4) {
        int r = r0 + rr;
        const float4* wrow = (const float4*)(Wfc + (size_t)r * H_DIM);
        float acc = 0.0f;
#pragma unroll
        for (int c = 0; c < 8; ++c) {
            float4 w4 = wrow[c * 64 + lane];
            float4 h4 = hv[c * 64 + lane];
            acc += w4.x * h4.x + w4.y * h4.y + w4.z * h4.z + w4.w * h4.w;
        }
#pragma unroll
        for (int off = 32; off > 0; off >>= 1) acc += __shfl_xor(acc, off, 64);
        if (lane == 0) logits[r] = acc + bfc[r];
    }
}

// ---------------------------------------------------------------------------
// Kernel 5: softmax over 4096 logits -> out
// ---------------------------------------------------------------------------
__global__ void softmax_kernel(const float* __restrict__ logits,
                               float* __restrict__ out) {
    __shared__ float sm[8];
    int tid = threadIdx.x, lane = tid & 63, wv = tid >> 6;
    float m = -1e30f;
    for (int i = tid; i < NGUESS; i += 256) m = fmaxf(m, logits[i]);
#pragma unroll
    for (int off = 32; off > 0; off >>= 1) m = fmaxf(m, __shfl_xor(m, off, 64));
    if (lane == 0) sm[wv] = m;
    __syncthreads();
    m = fmaxf(fmaxf(sm[0], sm[1]), fmaxf(sm[2], sm[3]));
    float s = 0.0f;
    for (int i = tid; i < NGUESS; i += 256) s += expf(logits[i] - m);
#pragma unroll
    for (int off = 32; off > 0; off >>= 1) s += __shfl_xor(s, off, 64);
    if (lane == 0) sm[4 + wv] = s;
    __syncthreads();
    s = sm[4] + sm[5] + sm[6] + sm[7];
    float inv = 1.0f / s;
    for (int i = tid; i < NGUESS; i += 256) out[i] = expf(logits[i] - m) * inv;
}

// ---------------------------------------------------------------------------
extern "C" void kernel_launch(void* const* d_in, const int* in_sizes, int n_in,
                              void* d_out, int out_size, void* d_ws, size_t ws_size,
                              hipStream_t stream) {
    const int*   guesses   = (const int*)d_in[0];
    const int*   feedbacks = (const int*)d_in[1];
    const float* gemb      = (const float*)d_in[2];
    const float* femb      = (const float*)d_in[3];
    const float* Wih       = (const float*)d_in[4];
    const float* Whh       = (const float*)d_in[5];
    const float* bih       = (const float*)d_in[6];
    const float* bhh       = (const float*)d_in[7];
    const float* Wfc       = (const float*)d_in[8];
    const float* bfc       = (const float*)d_in[9];

    float* ws     = (float*)d_ws;
    float* xs     = ws;                              // 512*2048 f   (4 MB)
    float* GX     = xs + (size_t)T_STEPS * H_DIM;    // 512*8192 f   (16 MB)
    u64*   hseq   = (u64*)(GX + (size_t)T_STEPS * G_DIM);  // 2*2048 u64
    float* hfinal = (float*)(hseq + 2 * H_DIM);      // 2048 f
    float* logits = hfinal + H_DIM;                  // 4096 f
    float* out    = (float*)d_out;

    // reset seq tags every call (graph replays include this) -> no ABA
    hipMemsetAsync(hseq, 0, 2 * H_DIM * sizeof(u64), stream);

    embed_kernel<<<T_STEPS, 256, 0, stream>>>(guesses, feedbacks, gemb, femb, xs);

    dim3 g2(G_DIM / 64, T_STEPS / 64);               // 128 x 8
    gx_gemm<<<g2, 256, 0, stream>>>(xs, Wih, bih, bhh, GX);

    {
        // cooperative launch solely for the co-residency guarantee
        void* args[] = { (void*)&Whh, (void*)&GX, (void*)&xs,
                         (void*)&hseq, (void*)&hfinal };
        hipLaunchCooperativeKernel((const void*)lstm_loop, dim3(NWG), dim3(1024),
                                   args, 0, stream);
    }

    fc_kernel<<<NGUESS / 16, 256, 0, stream>>>(Wfc, bfc, hfinal, logits);
    softmax_kernel<<<1, 256, 0, stream>>>(logits, out);
}